// Round 5
// baseline (3933.231 us; speedup 1.0000x reference)
//
#include <hip/hip_runtime.h>
#include <hip/hip_bf16.h>
#include <cstdint>

using bf16 = __hip_bfloat16;
using bf16x8 = __attribute__((ext_vector_type(8))) short;   // 8 bf16 = 4 VGPRs
using f32x4  = __attribute__((ext_vector_type(4))) float;

#define NHEADS 8
#define SEQ 49
#define CDIM 448
#define QLD 34     // q/k LDS row stride, elems (17 dw, odd -> conflict-light)
#define VLD2 130   // v LDS row stride, elems (65 dw, odd)
#define PFLD 52    // P row stride, f32
#define CLD2 136   // ctx row stride, elems (rows 16B-aligned for MFMA A-frags)

struct Smem {
    bf16* ql; bf16* kl; bf16* vl; bf16* ctxl;
    float* Pf; float* abl; unsigned char* idx8;
};

__device__ __forceinline__ short f2s(float x) {
    union { bf16 h; short s; } u; u.h = __float2bfloat16(x); return u.s;
}
__device__ __forceinline__ bf16x8 load8(const bf16* p) { return *(const bf16x8*)p; }
__device__ __forceinline__ bf16x8 load8(const float* p) {
    f32x4 a = *(const f32x4*)p;
    f32x4 b = *(const f32x4*)(p + 4);
    bf16x8 r;
    r[0]=f2s(a[0]); r[1]=f2s(a[1]); r[2]=f2s(a[2]); r[3]=f2s(a[3]);
    r[4]=f2s(b[0]); r[5]=f2s(b[1]); r[6]=f2s(b[2]); r[7]=f2s(b[3]);
    return r;
}
__device__ __forceinline__ float toF(bf16 x) { return __bfloat162float(x); }
__device__ __forceinline__ float toF(float x) { return x; }
__device__ __forceinline__ void storeT(bf16* p, float v) { *p = __float2bfloat16(v); }
__device__ __forceinline__ void storeT(float* p, float v) { *p = v; }
// bf16 pair unpack from one dword (little-endian: low short = even element)
__device__ __forceinline__ float blo(unsigned u) { return __uint_as_float(u << 16); }
__device__ __forceinline__ float bhi(unsigned u) { return __uint_as_float(u & 0xffff0000u); }

template <typename T>
__device__ __forceinline__
void body(const T* __restrict__ hs, const T* __restrict__ qkv_w,
          const T* __restrict__ qkv_b, const T* __restrict__ proj_w,
          const T* __restrict__ proj_b, const T* __restrict__ ab,
          const int* __restrict__ idx32, T* __restrict__ out, Smem s) {
    const int b   = blockIdx.x;
    const int tid = threadIdx.x;
    const int l   = tid & 63;
    const int w   = tid >> 6;          // wave 0..3
    const int lr  = l & 15;            // A/B-operand row within 16
    const int lk  = (l >> 4) * 8;      // A/B-operand k offset
    const int cm  = (l >> 4) * 4;      // C/D row base
    const int cn  = l & 15;            // C/D col

    // idxs: dword1==1 -> int32; dword1==0 -> int64 (values<=48, high words 0)
    const int istr = (idx32[1] == 0) ? 2 : 1;
    // FIX(R4->R5): abl has 392 entries; a single `if (tid < 392)` left 256..391
    // UNINITIALIZED (stale LDS: NaNs / huge values) -> heads 5..7 got garbage
    // biases. This was the R1..R4 corruption source.
    for (int i = tid; i < NHEADS * SEQ; i += 256) s.abl[i] = toF(ab[i]);
    for (int i = tid; i < SEQ * SEQ; i += 256)
        s.idx8[i] = (unsigned char)idx32[i * istr];
    // zero ctx pad rows 49..63 once (proj A-frags read them; contribute 0)
    for (int i = tid; i < (64 - SEQ) * CLD2; i += 256)
        s.ctxl[SEQ * CLD2 + i] = __float2bfloat16(0.f);

    f32x4 oacc[4][7] = {};   // persistent proj accumulator [mtile][ntile_j]
    const float scale = 0.17677669529663687f;  // 32^-0.5

    for (int h = 0; h < NHEADS; ++h) {
        // ========= QKV chunk GEMM (MFMA): cols [h*192, h*192+192), K=448 =========
        f32x4 qacc[3][4] = {};
        for (int ks = 0; ks < 14; ++ks) {
            const int k0 = ks * 32;
            bf16x8 af[4], bfr[3];
            #pragma unroll
            for (int mf = 0; mf < 4; ++mf) {
                int row = 16 * mf + lr; if (row > SEQ - 1) row = SEQ - 1;
                af[mf] = load8(hs + ((int64_t)b * SEQ + row) * CDIM + k0 + lk);
            }
            #pragma unroll
            for (int j = 0; j < 3; ++j) {
                const int n = h * 192 + (3 * w + j) * 16 + lr;
                bfr[j] = load8(qkv_w + (int64_t)n * CDIM + k0 + lk);
            }
            #pragma unroll
            for (int j = 0; j < 3; ++j)
                #pragma unroll
                for (int mf = 0; mf < 4; ++mf)
                    qacc[j][mf] = __builtin_amdgcn_mfma_f32_16x16x32_bf16(
                        af[mf], bfr[j], qacc[j][mf], 0, 0, 0);
        }
        // epilogue (C/D: row=16mf+cm+r, col=(3w+j)*16+cn): +bias, scatter q/k/v
        #pragma unroll
        for (int j = 0; j < 3; ++j) {
            const int c = (3 * w + j) * 16 + cn;              // 0..191 in head chunk
            const float bv = toF(qkv_b[h * 192 + c]);
            #pragma unroll
            for (int mf = 0; mf < 4; ++mf)
                #pragma unroll
                for (int r = 0; r < 4; ++r) {
                    const int row = 16 * mf + cm + r;          // token 0..63
                    const float v = qacc[j][mf][r] + bv;
                    if (row < SEQ) {
                        if (c < 32)      s.ql[row * QLD + c] = __float2bfloat16(v);
                        else if (c < 64) s.kl[row * QLD + (c - 32)] = __float2bfloat16(v);
                        else             s.vl[row * VLD2 + (c - 64)] = __float2bfloat16(v);
                    }
                }
        }
        __syncthreads();   // B1: q/k/v ready

        // ========= scores (VALU fp32): Pf[row][key] over real pairs only =========
        for (int p = tid; p < SEQ * SEQ; p += 256) {
            const int row = p / SEQ;
            const int key = p - row * SEQ;
            const unsigned* qr = (const unsigned*)(s.ql + row * QLD);
            const unsigned* kr = (const unsigned*)(s.kl + key * QLD);
            float d = 0.f;
            #pragma unroll
            for (int i = 0; i < 16; ++i) {
                const unsigned uq = qr[i], uk = kr[i];
                d += blo(uq) * blo(uk) + bhi(uq) * bhi(uk);
            }
            s.Pf[row * PFLD + key] = d * scale + s.abl[h * SEQ + s.idx8[p]];
        }
        __syncthreads();   // B2a: scores ready

        // ========= softmax (fp32, one thread per row) =========
        if (tid < SEQ) {
            float* rp = s.Pf + tid * PFLD;
            float mx = rp[0];
            for (int j = 1; j < SEQ; ++j) mx = fmaxf(mx, rp[j]);
            float sum = 0.f;
            for (int j = 0; j < SEQ; ++j) { const float e = __expf(rp[j] - mx); rp[j] = e; sum += e; }
            const float inv = 1.f / sum;
            for (int j = 0; j < SEQ; ++j) rp[j] *= inv;
        }
        __syncthreads();   // B2b: P ready (fp32)

        // ========= PV (VALU fp32): ctx[row][d], tasks = 49 rows x 8 d-blocks =========
        for (int p = tid; p < SEQ * 8; p += 256) {
            const int row = p >> 3;
            const int db  = p & 7;
            float acc[16];
            #pragma unroll
            for (int i = 0; i < 16; ++i) acc[i] = 0.f;
            for (int j = 0; j < SEQ; ++j) {
                const float pj = s.Pf[row * PFLD + j];
                const unsigned* vr = (const unsigned*)(s.vl + j * VLD2 + db * 16);
                #pragma unroll
                for (int i = 0; i < 8; ++i) {
                    const unsigned uv = vr[i];
                    acc[2 * i]     += pj * blo(uv);
                    acc[2 * i + 1] += pj * bhi(uv);
                }
            }
            #pragma unroll
            for (int i = 0; i < 16; ++i)
                s.ctxl[row * CLD2 + db * 16 + i] = __float2bfloat16(acc[i]);
        }
        __syncthreads();   // B3: ctx_h ready

        // ===== proj partial (MFMA): oacc += ctx_h[64x128] @ proj_w[:,h*128:+128]^T =====
        #pragma unroll
        for (int ks3 = 0; ks3 < 4; ++ks3) {
            bf16x8 ac[4], bw[7];
            #pragma unroll
            for (int mf = 0; mf < 4; ++mf)
                ac[mf] = *(const bf16x8*)(s.ctxl + (16 * mf + lr) * CLD2 + ks3 * 32 + lk);
            #pragma unroll
            for (int j = 0; j < 7; ++j) {
                const int n = (w * 7 + j) * 16 + lr;
                bw[j] = load8(proj_w + (int64_t)n * 1024 + h * 128 + ks3 * 32 + lk);
            }
            #pragma unroll
            for (int mf = 0; mf < 4; ++mf)
                #pragma unroll
                for (int j = 0; j < 7; ++j)
                    oacc[mf][j] = __builtin_amdgcn_mfma_f32_16x16x32_bf16(
                        ac[mf], bw[j], oacc[mf][j], 0, 0, 0);
        }
        __syncthreads();   // B4: safety barrier before next head's LDS writes
    }

    // ========= store: out[b*49+row][col] = oacc + proj_b =========
    #pragma unroll
    for (int j = 0; j < 7; ++j) {
        const int col = w * 112 + j * 16 + cn;                 // < 448 always
        const float pbv = toF(proj_b[col]);
        #pragma unroll
        for (int mf = 0; mf < 4; ++mf)
            #pragma unroll
            for (int r = 0; r < 4; ++r) {
                const int row = 16 * mf + cm + r;
                if (row < SEQ)
                    storeT(out + ((int64_t)b * SEQ + row) * CDIM + col,
                           oacc[mf][j][r] + pbv);
            }
    }
}

// dtype detector: low 16 bits of fp32 dwords are uniform mantissa bits; for bf16
// data they're a bf16 value with exponent in the small-value window.
__global__ void detect_dtype(const unsigned int* __restrict__ w, int* __restrict__ flag) {
    if (threadIdx.x == 0 && blockIdx.x == 0) {
        int cnt = 0;
        for (int i = 0; i < 256; ++i) {
            const unsigned e = (w[i] >> 7) & 0xFF;
            cnt += (e >= 0x40 && e <= 0x7D);
        }
        *flag = (cnt < 156) ? 1 : 0;   // 1 = fp32, 0 = bf16
    }
}

__global__ __launch_bounds__(256)
void fused_effattn(const void* hs, const void* qkv_w, const void* qkv_b,
                   const void* proj_w, const void* proj_b, const void* ab,
                   const int* idxs, void* out, const int* __restrict__ flag) {
    __shared__ __align__(16) bf16 ql[64 * QLD];
    __shared__ __align__(16) bf16 kl[64 * QLD];
    __shared__ __align__(16) bf16 vl[64 * VLD2];
    __shared__ __align__(16) bf16 ctxl[64 * CLD2];
    __shared__ __align__(16) float Pf[SEQ * PFLD];
    __shared__ float abl[NHEADS * SEQ];
    __shared__ unsigned char idx8[SEQ * SEQ];
    Smem s{ql, kl, vl, ctxl, Pf, abl, idx8};

    if (*flag) {
        body<float>((const float*)hs, (const float*)qkv_w, (const float*)qkv_b,
                    (const float*)proj_w, (const float*)proj_b, (const float*)ab,
                    idxs, (float*)out, s);
    } else {
        body<bf16>((const bf16*)hs, (const bf16*)qkv_w, (const bf16*)qkv_b,
                   (const bf16*)proj_w, (const bf16*)proj_b, (const bf16*)ab,
                   idxs, (bf16*)out, s);
    }
}

extern "C" void kernel_launch(void* const* d_in, const int* in_sizes, int n_in,
                              void* d_out, int out_size, void* d_ws, size_t ws_size,
                              hipStream_t stream) {
    int* flag = (int*)d_ws;
    detect_dtype<<<1, 64, 0, stream>>>((const unsigned int*)d_in[1], flag);
    fused_effattn<<<dim3(2048), dim3(256), 0, stream>>>(
        d_in[0], d_in[1], d_in[2], d_in[3], d_in[4], d_in[5],
        (const int*)d_in[6], d_out, flag);
}